// Round 10
// baseline (141.685 us; speedup 1.0000x reference)
//
#include <hip/hip_runtime.h>

#define BB 8
#define NN 2048
#define FF 64
#define LOG2E 1.4426950408889634f
#define RPB 32                       // rows per block
#define BPB (NN / RPB)               // producer blocks per batch = 64
#define NBLK (BB * NN / RPB)         // 512 blocks (capacity 1024 at 4/CU)

typedef float f32x4 __attribute__((ext_vector_type(4)));

__device__ __forceinline__ f32x4 vmax4(f32x4 a, f32x4 b) {
    f32x4 r;
    r.x = fmaxf(a.x, b.x); r.y = fmaxf(a.y, b.y);
    r.z = fmaxf(a.z, b.z); r.w = fmaxf(a.w, b.w);
    return r;
}

// Single launch. Block owns 32 rows of one batch.
//  P0: fold attn vectors (redundant per block, 16 KB L2 read)
//  P1: own rows' S (->LDS) and T (->global, released via fence+atomic flag)
//  barrier: spin until all 64 blocks of this batch published T
//  P2: batch E/F tables in LDS; factored exact softmax; streamed stores.
__global__ __launch_bounds__(256, 4) void gat_one(const float* __restrict__ enc,
                                                  const float* __restrict__ kmat,
                                                  const float* __restrict__ aks,
                                                  const float* __restrict__ akn,
                                                  float* __restrict__ T,
                                                  unsigned int* __restrict__ flags,
                                                  float* __restrict__ out) {
    __shared__ float Ez[NN];    // 2^t
    __shared__ float Fz[NN];    // 2^{0.2 t}
    __shared__ float ws[FF], wn[FF];
    __shared__ float sS[RPB];

    const int tid  = threadIdx.x;
    const int wave = tid >> 6, lane = tid & 63;
    const int row0 = blockIdx.x * RPB;
    const int b    = row0 >> 11;          // N = 2048

    // ---- P0: fold ----
    if (tid < FF) {
        float s = 0.f, t = 0.f;
        #pragma unroll
        for (int o = 0; o < FF; ++o) {
            float k = kmat[tid * FF + o];
            s += k * aks[o];
            t += k * akn[o];
        }
        ws[tid] = s;
        wn[tid] = t;
    }
    __syncthreads();

    // ---- P1: own 32 rows' scores ----
    if (tid < RPB) {
        const int g = row0 + tid;
        const f32x4* e4 = (const f32x4*)(enc + (size_t)g * FF);
        const f32x4* w4 = (const f32x4*)ws;
        const f32x4* v4 = (const f32x4*)wn;
        float s = 0.f, t = 0.f;
        #pragma unroll
        for (int j = 0; j < FF / 4; ++j) {
            f32x4 e = e4[j], w = w4[j], v = v4[j];
            s += e.x * w.x + e.y * w.y + e.z * w.z + e.w * w.w;
            t += e.x * v.x + e.y * v.y + e.z * v.z + e.w * v.w;
        }
        sS[tid] = s * LOG2E;
        T[g]    = t * LOG2E;
    }
    __threadfence();              // publish T (agent scope)
    __syncthreads();
    if (tid == 0) {
        __hip_atomic_fetch_add(&flags[b], 1u, __ATOMIC_RELEASE,
                               __HIP_MEMORY_SCOPE_AGENT);
        while (__hip_atomic_load(&flags[b], __ATOMIC_ACQUIRE,
                                 __HIP_MEMORY_SCOPE_AGENT) < (unsigned)BPB) {
            __builtin_amdgcn_s_sleep(2);
        }
    }
    __syncthreads();
    __threadfence();              // acquire: invalidate stale cached T lines

    // ---- P2: batch E/F tables (8 elements / thread) ----
    const f32x4* t4 = (const f32x4*)(T + (size_t)b * NN);
    f32x4* EL = (f32x4*)Ez;
    f32x4* FL = (f32x4*)Fz;
    {
        f32x4 ta = t4[tid];
        f32x4 tb = t4[tid + 256];
        f32x4 E, F;
        E.x = __builtin_exp2f(ta.x); E.y = __builtin_exp2f(ta.y);
        E.z = __builtin_exp2f(ta.z); E.w = __builtin_exp2f(ta.w);
        F.x = __builtin_exp2f(0.2f * ta.x); F.y = __builtin_exp2f(0.2f * ta.y);
        F.z = __builtin_exp2f(0.2f * ta.z); F.w = __builtin_exp2f(0.2f * ta.w);
        EL[tid] = E; FL[tid] = F;
        E.x = __builtin_exp2f(tb.x); E.y = __builtin_exp2f(tb.y);
        E.z = __builtin_exp2f(tb.z); E.w = __builtin_exp2f(tb.w);
        F.x = __builtin_exp2f(0.2f * tb.x); F.y = __builtin_exp2f(0.2f * tb.y);
        F.z = __builtin_exp2f(0.2f * tb.z); F.w = __builtin_exp2f(0.2f * tb.w);
        EL[tid + 256] = E; FL[tid + 256] = F;
    }
    __syncthreads();

    // ---- P3: 8 rows per wave; sum pass then store pass ----
    float A[8], Bc[8], ls[8];
    #pragma unroll
    for (int r = 0; r < 8; ++r) {
        const float s = sS[wave * 8 + r];
        A[r]  = __builtin_exp2f(s);          // 2^s
        Bc[r] = __builtin_exp2f(0.2f * s);   // 2^{0.2 s}
        float l = 0.f;
        #pragma unroll
        for (int j = 0; j < 8; ++j) {
            f32x4 E = EL[lane + 64 * j];
            f32x4 F = FL[lane + 64 * j];
            f32x4 e = vmax4(A[r] * E, Bc[r] * F);
            l += (e.x + e.y) + (e.z + e.w);
        }
        ls[r] = l;
    }
    #pragma unroll
    for (int o = 32; o > 0; o >>= 1) {       // 8 independent chains interleaved
        #pragma unroll
        for (int r = 0; r < 8; ++r) ls[r] += __shfl_xor(ls[r], o, 64);
    }
    #pragma unroll
    for (int r = 0; r < 8; ++r) {
        const float inv = 1.f / ls[r];
        A[r]  *= inv;
        Bc[r] *= inv;
    }

    const int wrow0 = row0 + wave * 8;
    #pragma unroll
    for (int r = 0; r < 8; ++r) {
        f32x4* o4 = (f32x4*)(out + (size_t)(wrow0 + r) * NN);
        #pragma unroll
        for (int j = 0; j < 8; ++j) {
            f32x4 E = EL[lane + 64 * j];
            f32x4 F = FL[lane + 64 * j];
            o4[lane + 64 * j] = vmax4(A[r] * E, Bc[r] * F);
        }
    }
}

extern "C" void kernel_launch(void* const* d_in, const int* in_sizes, int n_in,
                              void* d_out, int out_size, void* d_ws, size_t ws_size,
                              hipStream_t stream) {
    const float* enc  = (const float*)d_in[0];  // [B,N,F]
    const float* kmat = (const float*)d_in[1];  // [F,1,F]
    const float* aks  = (const float*)d_in[2];  // [F,1,1]
    const float* akn  = (const float*)d_in[3];  // [F,1,1]
    float* out = (float*)d_out;                 // [B,N,N]

    float* W = (float*)d_ws;
    float* T = W;                                        // B*N floats = 64 KB
    unsigned int* flags = (unsigned int*)(W + BB * NN);  // 8 u32

    hipMemsetAsync((void*)flags, 0, BB * sizeof(unsigned int), stream);
    gat_one<<<NBLK, 256, 0, stream>>>(enc, kmat, aks, akn, T, flags, out);
}

// Round 11
// 54.197 us; speedup vs baseline: 2.6143x; 2.6143x over previous
//
#include <hip/hip_runtime.h>

#define BB 8
#define NN 2048
#define FF 64
#define LOG2E 1.4426950408889634f
#define ROWS_PER_WAVE 4

typedef float f32x4 __attribute__((ext_vector_type(4)));

// ---------------- Kernel A: fused fold + per-node scores (prescaled) ---------
__global__ __launch_bounds__(256) void scores_fused(const float* __restrict__ enc,
                                                    const float* __restrict__ kmat,
                                                    const float* __restrict__ aks,
                                                    const float* __restrict__ akn,
                                                    float* __restrict__ S,
                                                    float* __restrict__ T) {
    __shared__ float ws[FF], wn[FF];
    const int tid = threadIdx.x;
    if (tid < FF) {
        float s = 0.f, t = 0.f;
        #pragma unroll
        for (int o = 0; o < FF; ++o) {
            float k = kmat[tid * FF + o];
            s += k * aks[o];
            t += k * akn[o];
        }
        ws[tid] = s;
        wn[tid] = t;
    }
    __syncthreads();

    const int g = blockIdx.x * 256 + tid;
    const f32x4* e4 = (const f32x4*)(enc + (size_t)g * FF);
    const f32x4* w4 = (const f32x4*)ws;
    const f32x4* v4 = (const f32x4*)wn;
    float s = 0.f, t = 0.f;
    #pragma unroll
    for (int j = 0; j < FF / 4; ++j) {
        f32x4 e = e4[j];
        f32x4 w = w4[j];
        f32x4 v = v4[j];
        s += e.x * w.x + e.y * w.y + e.z * w.z + e.w * w.w;
        t += e.x * v.x + e.y * v.y + e.z * v.z + e.w * v.w;
    }
    S[g] = s * LOG2E;
    T[g] = t * LOG2E;
}

// ---------------- Kernel B: R7 kernel + DIAGNOSTIC double store pass ---------
__device__ __forceinline__ float waveMax(float v) {
    #pragma unroll
    for (int o = 32; o > 0; o >>= 1) v = fmaxf(v, __shfl_xor(v, o, 64));
    return v;
}
__device__ __forceinline__ float lk(float x) { return fmaxf(x, 0.2f * x); }

__global__ __launch_bounds__(256) void softmax_kernel(const float* __restrict__ S,
                                                      const float* __restrict__ T,
                                                      float* __restrict__ out) {
    const int wave = threadIdx.x >> 6;
    const int lane = threadIdx.x & 63;
    const int row0 = (blockIdx.x * 4 + wave) * ROWS_PER_WAVE;  // same batch
    const int b    = row0 >> 11;                               // N = 2048

    const f32x4* t4 = (const f32x4*)(T + (size_t)b * NN);

    f32x4 t[8];
    float tm = -3.4e38f;
    #pragma unroll
    for (int j = 0; j < 8; ++j) {
        t[j] = t4[lane + 64 * j];
        tm = fmaxf(tm, fmaxf(fmaxf(t[j].x, t[j].y), fmaxf(t[j].z, t[j].w)));
    }
    const float tmax = waveMax(tm);

    f32x4 E[8], F[8];
    #pragma unroll
    for (int j = 0; j < 8; ++j) {
        f32x4 d;
        d.x = t[j].x - tmax; d.y = t[j].y - tmax;
        d.z = t[j].z - tmax; d.w = t[j].w - tmax;
        E[j].x = __builtin_exp2f(d.x); E[j].y = __builtin_exp2f(d.y);
        E[j].z = __builtin_exp2f(d.z); E[j].w = __builtin_exp2f(d.w);
        F[j].x = __builtin_exp2f(0.2f * d.x); F[j].y = __builtin_exp2f(0.2f * d.y);
        F[j].z = __builtin_exp2f(0.2f * d.z); F[j].w = __builtin_exp2f(0.2f * d.w);
    }

    float A[ROWS_PER_WAVE], Bc[ROWS_PER_WAVE], ls[ROWS_PER_WAVE];
    #pragma unroll
    for (int r = 0; r < ROWS_PER_WAVE; ++r) {
        const int row = row0 + r;
        const float s = S[row];
        const float u = s + tmax;
        const float M = lk(u);
        A[r]  = __builtin_exp2f(u - M);
        Bc[r] = __builtin_exp2f(0.2f * u - M);
        float l = 0.f;
        #pragma unroll
        for (int j = 0; j < 8; ++j) {
            float ex = fmaxf(A[r] * E[j].x, Bc[r] * F[j].x);
            float ey = fmaxf(A[r] * E[j].y, Bc[r] * F[j].y);
            float ez = fmaxf(A[r] * E[j].z, Bc[r] * F[j].z);
            float ew = fmaxf(A[r] * E[j].w, Bc[r] * F[j].w);
            l += (ex + ey) + (ez + ew);
        }
        ls[r] = l;
    }
    #pragma unroll
    for (int o = 32; o > 0; o >>= 1) {
        #pragma unroll
        for (int r = 0; r < ROWS_PER_WAVE; ++r) ls[r] += __shfl_xor(ls[r], o, 64);
    }
    #pragma unroll
    for (int r = 0; r < ROWS_PER_WAVE; ++r) {
        const float inv = 1.f / ls[r];
        A[r]  *= inv;
        Bc[r] *= inv;
    }

    // ---- store pass 1 ----
    #pragma unroll
    for (int r = 0; r < ROWS_PER_WAVE; ++r) {
        f32x4* o4 = (f32x4*)(out + (size_t)(row0 + r) * NN);
        #pragma unroll
        for (int j = 0; j < 8; ++j) {
            f32x4 o;
            o.x = fmaxf(A[r] * E[j].x, Bc[r] * F[j].x);
            o.y = fmaxf(A[r] * E[j].y, Bc[r] * F[j].y);
            o.z = fmaxf(A[r] * E[j].z, Bc[r] * F[j].z);
            o.w = fmaxf(A[r] * E[j].w, Bc[r] * F[j].w);
            o4[lane + 64 * j] = o;
        }
    }
    __syncthreads();   // makes pass-1 stores observable -> no dead-store elim
    // ---- store pass 2: identical values (DIAGNOSTIC: measures pure store cost)
    #pragma unroll
    for (int r = 0; r < ROWS_PER_WAVE; ++r) {
        f32x4* o4 = (f32x4*)(out + (size_t)(row0 + r) * NN);
        #pragma unroll
        for (int j = 0; j < 8; ++j) {
            f32x4 o;
            o.x = fmaxf(A[r] * E[j].x, Bc[r] * F[j].x);
            o.y = fmaxf(A[r] * E[j].y, Bc[r] * F[j].y);
            o.z = fmaxf(A[r] * E[j].z, Bc[r] * F[j].z);
            o.w = fmaxf(A[r] * E[j].w, Bc[r] * F[j].w);
            o4[lane + 64 * j] = o;
        }
    }
}

extern "C" void kernel_launch(void* const* d_in, const int* in_sizes, int n_in,
                              void* d_out, int out_size, void* d_ws, size_t ws_size,
                              hipStream_t stream) {
    const float* enc  = (const float*)d_in[0];  // [B,N,F]
    const float* kmat = (const float*)d_in[1];  // [F,1,F]
    const float* aks  = (const float*)d_in[2];  // [F,1,1]
    const float* akn  = (const float*)d_in[3];  // [F,1,1]
    float* out = (float*)d_out;                 // [B,N,N]

    float* W = (float*)d_ws;
    float* S = W;                 // B*N = 16384
    float* T = W + BB * NN;       // 16384

    scores_fused<<<BB * NN / 256, 256, 0, stream>>>(enc, kmat, aks, akn, S, T);
    softmax_kernel<<<BB * NN / (4 * ROWS_PER_WAVE), 256, 0, stream>>>(S, T, out);
}